// Round 1
// baseline (525.369 us; speedup 1.0000x reference)
//
#include <hip/hip_runtime.h>

// ---------------- constants ----------------
#define NROWS 16384
#define NF 39
#define NV 100000
#define NE 16
#define HID 400
#define K1 624
#define K1P 640   // padded
#define K2P 448   // padded 400 -> 448
#define BN_EPS 1e-5f

typedef short short8v __attribute__((ext_vector_type(8)));
typedef float float4v __attribute__((ext_vector_type(4)));

__device__ __forceinline__ float bf2f(unsigned short u) {
    unsigned int x = ((unsigned int)u) << 16;
    return __uint_as_float(x);
}
__device__ __forceinline__ unsigned short f2bf(float f) {
    unsigned int x = __float_as_uint(f);
    unsigned int r = (x + 0x7FFFu + ((x >> 16) & 1u)) >> 16;
    return (unsigned short)r;
}

// ---------------- embed: gather + FM terms + h0 (bf16, padded to 640) ----------------
__global__ __launch_bounds__(64) void embed_kernel(const int* __restrict__ Xi,
                                                   const float* __restrict__ Xv,
                                                   const float* __restrict__ emb1,
                                                   const float* __restrict__ emb2,
                                                   unsigned short* __restrict__ h0,
                                                   float* __restrict__ f12) {
    int n = blockIdx.x;
    int tid = threadIdx.x;
    __shared__ int sidx[NF];
    __shared__ float sxv[NF];
    __shared__ float sx[NF][NE];
    __shared__ float srn[NE];
    if (tid < NF) {
        sidx[tid] = Xi[n * NF + tid];
        sxv[tid] = Xv[n * NF + tid];
    }
    __syncthreads();
    for (int i = tid; i < NF * NE; i += 64) {
        int f = i >> 4, e = i & 15;
        size_t off = ((size_t)f * NV + (size_t)sidx[f]) * NE + e;
        sx[f][e] = emb2[off] * sxv[f];
    }
    __syncthreads();
    float f2 = 0.f;
    if (tid < NE) {
        float ss = 0.f, sm = 0.f;
        #pragma unroll
        for (int f = 0; f < NF; ++f) {
            float v = sx[f][tid];
            ss += v * v;
            sm += v;
        }
        float norm = fmaxf(sqrtf(ss), 1e-12f);
        float rn = 1.f / norm;
        srn[tid] = rn;
        float s = sm * rn;
        f2 = 0.5f * (s * s - ss * rn * rn);
    }
    float f1 = 0.f;
    if (tid < NF) {
        f1 = emb1[(size_t)tid * NV + (size_t)sidx[tid]] * sxv[tid];
    }
    float tot = f1 + f2;
    #pragma unroll
    for (int o = 32; o; o >>= 1) tot += __shfl_down(tot, o, 64);
    if (tid == 0) f12[n] = tot;
    __syncthreads();
    for (int i = tid; i < K1P; i += 64) {
        unsigned short o = 0;
        if (i < NF * NE) {
            int f = i >> 4, e = i & 15;
            o = f2bf(sx[f][e] * srn[e]);
        }
        h0[(size_t)n * K1P + i] = o;
    }
}

// ---------------- weight fp32 -> bf16 with K padding ----------------
__global__ void convertw_kernel(const float* __restrict__ W, unsigned short* __restrict__ Wb,
                                int K, int Kt) {
    int r = blockIdx.x;
    int k = threadIdx.x;
    if (k < Kt)
        Wb[(size_t)r * Kt + k] = (k < K) ? f2bf(W[(size_t)r * K + k]) : (unsigned short)0;
}

// ---------------- bf16 MFMA GEMM: C[m,n] = sum_k A[m,k] * W[n,k] + bias[n] ----------------
// BM=128, BN=80 (5 n-frags), BK=64. grid (M/128, 400/80=5), block 256 (4 waves).
#define BM 128
#define BNT 80
#define BK 64
#define LDS_S 72  // padded LDS k-stride (bf16 elems)

__global__ __launch_bounds__(256) void gemm_kernel(const unsigned short* __restrict__ A, int lda,
                                                   const unsigned short* __restrict__ W, int ldw,
                                                   const float* __restrict__ bias,
                                                   unsigned short* __restrict__ C, int ldc,
                                                   int Kt) {
    __shared__ __align__(16) unsigned short As[BM * LDS_S];
    __shared__ __align__(16) unsigned short Bs[BNT * LDS_S];
    int tid = threadIdx.x;
    int wave = tid >> 6, lane = tid & 63;
    int quad = lane >> 4, l16 = lane & 15;
    int m0 = blockIdx.x * BM;
    int n0 = blockIdx.y * BNT;

    float4v acc[2][5];
    #pragma unroll
    for (int i = 0; i < 2; ++i)
        #pragma unroll
        for (int j = 0; j < 5; ++j)
            acc[i][j] = (float4v){0.f, 0.f, 0.f, 0.f};

    for (int kt = 0; kt < Kt; kt += BK) {
        __syncthreads();
        // stage A: 128 rows x 64 bf16 = 1024 x 16B vectors
        #pragma unroll
        for (int v = tid; v < BM * 8; v += 256) {
            int r = v >> 3, kv = (v & 7) * 8;
            short8v val = *(const short8v*)(A + (size_t)(m0 + r) * lda + kt + kv);
            *(short8v*)(As + r * LDS_S + kv) = val;
        }
        // stage B (W rows): 80 rows x 64 bf16 = 640 x 16B vectors
        for (int v = tid; v < BNT * 8; v += 256) {
            int r = v >> 3, kv = (v & 7) * 8;
            short8v val = *(const short8v*)(W + (size_t)(n0 + r) * ldw + kt + kv);
            *(short8v*)(Bs + r * LDS_S + kv) = val;
        }
        __syncthreads();
        #pragma unroll
        for (int kk = 0; kk < BK; kk += 32) {
            short8v af[2], bfr[5];
            #pragma unroll
            for (int i = 0; i < 2; ++i)
                af[i] = *(const short8v*)(As + (wave * 32 + i * 16 + l16) * LDS_S + kk + quad * 8);
            #pragma unroll
            for (int j = 0; j < 5; ++j)
                bfr[j] = *(const short8v*)(Bs + (j * 16 + l16) * LDS_S + kk + quad * 8);
            #pragma unroll
            for (int i = 0; i < 2; ++i)
                #pragma unroll
                for (int j = 0; j < 5; ++j)
                    acc[i][j] = __builtin_amdgcn_mfma_f32_16x16x32_bf16(af[i], bfr[j], acc[i][j], 0, 0, 0);
        }
    }
    // epilogue: C/D layout col=lane&15, row=quad*4+reg
    #pragma unroll
    for (int i = 0; i < 2; ++i) {
        #pragma unroll
        for (int j = 0; j < 5; ++j) {
            int col = n0 + j * 16 + l16;
            float bv = bias[col];
            #pragma unroll
            for (int r = 0; r < 4; ++r) {
                int row = m0 + wave * 32 + i * 16 + quad * 4 + r;
                C[(size_t)row * ldc + col] = f2bf(acc[i][j][r] + bv);
            }
        }
    }
}

// ---------------- column stats (sum, sumsq) via atomics ----------------
__global__ __launch_bounds__(512) void stats_kernel(const unsigned short* __restrict__ H,
                                                    float* __restrict__ sums) {
    int j = threadIdx.x;
    if (j >= HID) return;
    int r0 = blockIdx.x * 256;
    float s = 0.f, sq = 0.f;
    for (int r = 0; r < 256; ++r) {
        float v = bf2f(H[(size_t)(r0 + r) * HID + j]);
        s += v;
        sq += v * v;
    }
    atomicAdd(&sums[j], s);
    atomicAdd(&sums[HID + j], sq);
}

__global__ void finalize_kernel(const float* __restrict__ sums, const float* __restrict__ g,
                                const float* __restrict__ bt, float* __restrict__ scsh) {
    int j = threadIdx.x;
    if (j >= HID) return;
    const float invN = 1.f / (float)NROWS;
    float mu = sums[j] * invN;
    float var = sums[HID + j] * invN - mu * mu;
    float rstd = rsqrtf(var + BN_EPS);
    float sc = g[j] * rstd;
    scsh[j] = sc;
    scsh[HID + j] = bt[j] - mu * sc;
}

// ---------------- apply BN+ReLU -> bf16 activation (padded to 448) ----------------
__global__ __launch_bounds__(448) void apply_kernel(const unsigned short* __restrict__ H,
                                                    const float* __restrict__ scsh,
                                                    unsigned short* __restrict__ Aout) {
    int n = blockIdx.x;
    int k = threadIdx.x;
    unsigned short o = 0;
    if (k < HID) {
        float v = bf2f(H[(size_t)n * HID + k]) * scsh[k] + scsh[HID + k];
        o = f2bf(fmaxf(v, 0.f));
    }
    Aout[(size_t)n * K2P + k] = o;
}

// ---------------- final: out[n] = f12[n] + sum_j relu(bn3(h3)) + bias ----------------
__global__ __launch_bounds__(256) void final_kernel(const unsigned short* __restrict__ H3,
                                                    const float* __restrict__ scsh,
                                                    const float* __restrict__ f12,
                                                    const float* __restrict__ bias,
                                                    float* __restrict__ out) {
    int wave = threadIdx.x >> 6, lane = threadIdx.x & 63;
    int n = blockIdx.x * 4 + wave;
    float acc = 0.f;
    for (int k = lane; k < HID; k += 64) {
        float v = bf2f(H3[(size_t)n * HID + k]) * scsh[k] + scsh[HID + k];
        acc += fmaxf(v, 0.f);
    }
    #pragma unroll
    for (int o = 32; o; o >>= 1) acc += __shfl_down(acc, o, 64);
    if (lane == 0) out[n] = acc + f12[n] + bias[0];
}

// ---------------- launch ----------------
extern "C" void kernel_launch(void* const* d_in, const int* in_sizes, int n_in,
                              void* d_out, int out_size, void* d_ws, size_t ws_size,
                              hipStream_t stream) {
    const int* Xi = (const int*)d_in[0];
    const float* Xv = (const float*)d_in[1];
    const float* emb1 = (const float*)d_in[2];
    const float* emb2 = (const float*)d_in[3];
    const float* W1 = (const float*)d_in[4];
    const float* b1 = (const float*)d_in[5];
    const float* g1 = (const float*)d_in[6];
    const float* bt1 = (const float*)d_in[7];
    const float* W2 = (const float*)d_in[8];
    const float* b2 = (const float*)d_in[9];
    const float* g2 = (const float*)d_in[10];
    const float* bt2 = (const float*)d_in[11];
    const float* W3 = (const float*)d_in[12];
    const float* b3 = (const float*)d_in[13];
    const float* g3 = (const float*)d_in[14];
    const float* bt3 = (const float*)d_in[15];
    const float* bias = (const float*)d_in[16];

    char* ws = (char*)d_ws;
    // workspace layout (bytes)
    size_t o_f12 = 0;                                    // 16384*4 = 65536
    size_t o_h0 = 65536;                                 // 16384*640*2 = 20971520
    size_t o_h1 = o_h0 + (size_t)NROWS * K1P * 2;        // 16384*400*2 = 13107200
    size_t o_a1 = o_h1 + (size_t)NROWS * HID * 2;        // 16384*448*2 = 14680064
    size_t o_w1 = o_a1 + (size_t)NROWS * K2P * 2;        // 400*640*2
    size_t o_w2 = o_w1 + (size_t)HID * K1P * 2;          // 400*448*2
    size_t o_w3 = o_w2 + (size_t)HID * K2P * 2;
    size_t o_sums = o_w3 + (size_t)HID * K2P * 2;        // 3 * 800 * 4
    size_t o_scsh = o_sums + 3 * 800 * 4;                // 3 * 800 * 4
    // aliases (dead-buffer reuse)
    size_t o_h2 = o_h0;
    size_t o_a2 = o_a1;
    size_t o_h3 = o_h1;

    float* f12 = (float*)(ws + o_f12);
    unsigned short* h0 = (unsigned short*)(ws + o_h0);
    unsigned short* h1 = (unsigned short*)(ws + o_h1);
    unsigned short* a1 = (unsigned short*)(ws + o_a1);
    unsigned short* h2 = (unsigned short*)(ws + o_h2);
    unsigned short* a2 = (unsigned short*)(ws + o_a2);
    unsigned short* h3 = (unsigned short*)(ws + o_h3);
    unsigned short* w1b = (unsigned short*)(ws + o_w1);
    unsigned short* w2b = (unsigned short*)(ws + o_w2);
    unsigned short* w3b = (unsigned short*)(ws + o_w3);
    float* sums1 = (float*)(ws + o_sums);
    float* sums2 = sums1 + 800;
    float* sums3 = sums2 + 800;
    float* scsh1 = (float*)(ws + o_scsh);
    float* scsh2 = scsh1 + 800;
    float* scsh3 = scsh2 + 800;
    float* out = (float*)d_out;

    hipMemsetAsync(ws + o_sums, 0, 3 * 800 * 4, stream);

    // weight conversion
    convertw_kernel<<<HID, K1P, 0, stream>>>(W1, w1b, K1, K1P);
    convertw_kernel<<<HID, K2P, 0, stream>>>(W2, w2b, HID, K2P);
    convertw_kernel<<<HID, K2P, 0, stream>>>(W3, w3b, HID, K2P);

    // embedding + FM terms
    embed_kernel<<<NROWS, 64, 0, stream>>>(Xi, Xv, emb1, emb2, h0, f12);

    dim3 ggrid(NROWS / BM, HID / BNT);

    // layer 1
    gemm_kernel<<<ggrid, 256, 0, stream>>>(h0, K1P, w1b, K1P, b1, h1, HID, K1P);
    stats_kernel<<<64, 512, 0, stream>>>(h1, sums1);
    finalize_kernel<<<1, 448, 0, stream>>>(sums1, g1, bt1, scsh1);
    apply_kernel<<<NROWS, K2P, 0, stream>>>(h1, scsh1, a1);

    // layer 2
    gemm_kernel<<<ggrid, 256, 0, stream>>>(a1, K2P, w2b, K2P, b2, h2, HID, K2P);
    stats_kernel<<<64, 512, 0, stream>>>(h2, sums2);
    finalize_kernel<<<1, 448, 0, stream>>>(sums2, g2, bt2, scsh2);
    apply_kernel<<<NROWS, K2P, 0, stream>>>(h2, scsh2, a2);

    // layer 3
    gemm_kernel<<<ggrid, 256, 0, stream>>>(a2, K2P, w3b, K2P, b3, h3, HID, K2P);
    stats_kernel<<<64, 512, 0, stream>>>(h3, sums3);
    finalize_kernel<<<1, 448, 0, stream>>>(sums3, g3, bt3, scsh3);

    // final output
    final_kernel<<<NROWS / 4, 256, 0, stream>>>(h3, scsh3, f12, bias, out);
}

// Round 2
// 457.238 us; speedup vs baseline: 1.1490x; 1.1490x over previous
//
#include <hip/hip_runtime.h>

// ---------------- constants ----------------
#define NROWS 16384
#define NF 39
#define NV 100000
#define NE 16
#define HID 400
#define K1 624     // real K of layer 1 (39*16)
#define K1T 640    // padded K-tile span for layer 1
#define K2T 448    // padded K-tile span for layers 2/3 (real 400)
#define BN_EPS 1e-5f

typedef short short8v __attribute__((ext_vector_type(8)));
typedef float float4v __attribute__((ext_vector_type(4)));

__device__ __forceinline__ float bf2f(unsigned short u) {
    unsigned int x = ((unsigned int)u) << 16;
    return __uint_as_float(x);
}
__device__ __forceinline__ unsigned short f2bf(float f) {
    unsigned int x = __float_as_uint(f);
    unsigned int r = (x + 0x7FFFu + ((x >> 16) & 1u)) >> 16;
    return (unsigned short)r;
}

// ---------------- embed: float4 gather + FM terms + h0 (bf16, unpadded 624) ----------------
// 4 samples per block, one wave per sample.
__global__ __launch_bounds__(256) void embed_kernel(const int* __restrict__ Xi,
                                                    const float* __restrict__ Xv,
                                                    const float* __restrict__ emb1,
                                                    const float* __restrict__ emb2,
                                                    unsigned short* __restrict__ h0,
                                                    float* __restrict__ f12) {
    int wave = threadIdx.x >> 6, lane = threadIdx.x & 63;
    int n = blockIdx.x * 4 + wave;
    __shared__ int sidx[4][NF + 1];
    __shared__ float sxv[4][NF + 1];
    __shared__ __align__(16) float sx[4][NF * NE];   // 624 floats per sample
    __shared__ float srn[4][NE];
    if (lane < NF) {
        sidx[wave][lane] = Xi[n * NF + lane];
        sxv[wave][lane] = Xv[n * NF + lane];
    }
    __syncthreads();
    // gather: 39 rows x 16 floats = 156 float4 per sample
    const float4* e2 = (const float4*)emb2;
    for (int i = lane; i < NF * 4; i += 64) {
        int f = i >> 2, q = i & 3;
        float4 v = e2[((size_t)f * NV + (size_t)sidx[wave][f]) * 4 + q];
        float m = sxv[wave][f];
        float4 o; o.x = v.x * m; o.y = v.y * m; o.z = v.z * m; o.w = v.w * m;
        *(float4*)&sx[wave][f * NE + q * 4] = o;
    }
    __syncthreads();
    float f2 = 0.f;
    if (lane < NE) {
        float ss = 0.f, sm = 0.f;
        #pragma unroll
        for (int f = 0; f < NF; ++f) {
            float v = sx[wave][f * NE + lane];
            ss += v * v;
            sm += v;
        }
        float rn = 1.f / fmaxf(sqrtf(ss), 1e-12f);
        srn[wave][lane] = rn;
        float s = sm * rn;
        f2 = 0.5f * (s * s - ss * rn * rn);
    }
    float f1 = 0.f;
    if (lane < NF) {
        f1 = emb1[(size_t)lane * NV + (size_t)sidx[wave][lane]] * sxv[wave][lane];
    }
    float tot = f1 + f2;
    #pragma unroll
    for (int o = 32; o; o >>= 1) tot += __shfl_down(tot, o, 64);
    if (lane == 0) f12[n] = tot;
    __syncthreads();
    for (int i = lane; i < NF * NE; i += 64)
        h0[(size_t)n * K1 + i] = f2bf(sx[wave][i] * srn[wave][i & 15]);
}

// ---------------- merged weight fp32 -> bf16 with K padding ----------------
__global__ __launch_bounds__(640) void convertw_kernel(const float* __restrict__ W1,
                                                       const float* __restrict__ W2,
                                                       const float* __restrict__ W3,
                                                       unsigned short* __restrict__ w1b,
                                                       unsigned short* __restrict__ w2b,
                                                       unsigned short* __restrict__ w3b) {
    int r = blockIdx.x, which = blockIdx.y, k = threadIdx.x;
    const float* W; unsigned short* O; int K, Kt;
    if (which == 0) { W = W1; O = w1b; K = K1;  Kt = K1T; }
    else if (which == 1) { W = W2; O = w2b; K = HID; Kt = K2T; }
    else { W = W3; O = w3b; K = HID; Kt = K2T; }
    if (k < Kt)
        O[(size_t)r * Kt + k] = (k < K) ? f2bf(W[(size_t)r * K + k]) : (unsigned short)0;
}

// ---------------- bf16 MFMA GEMM with fused BN-apply (on A) and fused BN-stats (on C) ------
// C[m,n] = sum_k T(A[m,k]) * W[n,k] + bias[n];  T = identity or relu(x*sc+sh)
// Also atomically accumulates per-column sum and sumsq of C into `sums`.
// BM=128, BNT=80, BK=64. grid (128, 5), block 256 (4 waves).
#define BM 128
#define BNT 80
#define BK 64
#define LDS_S 72  // padded LDS k-stride (bf16 elems)

template <bool FUSE_BN>
__global__ __launch_bounds__(256) void gemm_kernel(const unsigned short* __restrict__ A, int lda, int Kreal,
                                                   const unsigned short* __restrict__ W, int ldw,
                                                   const float* __restrict__ bias,
                                                   const float* __restrict__ scsh,
                                                   unsigned short* __restrict__ C, int ldc,
                                                   int Kt,
                                                   float* __restrict__ sums) {
    __shared__ __align__(16) unsigned short As[BM * LDS_S];
    __shared__ __align__(16) unsigned short Bs[BNT * LDS_S];
    __shared__ float ssc[K2T], ssh[K2T];
    __shared__ float sred[4][5][16], qred[4][5][16];
    int tid = threadIdx.x;
    int wave = tid >> 6, lane = tid & 63;
    int quad = lane >> 4, l16 = lane & 15;
    int m0 = blockIdx.x * BM;
    int n0 = blockIdx.y * BNT;

    if (FUSE_BN) {
        for (int i = tid; i < K2T; i += 256) {
            ssc[i] = (i < HID) ? scsh[i] : 0.f;
            ssh[i] = (i < HID) ? scsh[HID + i] : 0.f;
        }
    }

    float4v acc[2][5];
    #pragma unroll
    for (int i = 0; i < 2; ++i)
        #pragma unroll
        for (int j = 0; j < 5; ++j)
            acc[i][j] = (float4v){0.f, 0.f, 0.f, 0.f};

    for (int kt = 0; kt < Kt; kt += BK) {
        __syncthreads();
        // stage A: 128 rows x 8 vec16B
        #pragma unroll
        for (int v = tid; v < BM * 8; v += 256) {
            int r = v >> 3, kv = (v & 7) * 8;
            int k = kt + kv;
            short8v val;
            if (k < Kreal) {
                val = *(const short8v*)(A + (size_t)(m0 + r) * lda + k);
                if (FUSE_BN) {
                    #pragma unroll
                    for (int e = 0; e < 8; ++e) {
                        float x = bf2f((unsigned short)val[e]);
                        float y = fmaxf(x * ssc[k + e] + ssh[k + e], 0.f);
                        val[e] = (short)f2bf(y);
                    }
                }
            } else {
                val = (short8v){0,0,0,0,0,0,0,0};
            }
            *(short8v*)(As + r * LDS_S + kv) = val;
        }
        // stage B (W rows, pre-padded): 80 rows x 8 vec16B
        for (int v = tid; v < BNT * 8; v += 256) {
            int r = v >> 3, kv = (v & 7) * 8;
            short8v val = *(const short8v*)(W + (size_t)(n0 + r) * ldw + kt + kv);
            *(short8v*)(Bs + r * LDS_S + kv) = val;
        }
        __syncthreads();
        #pragma unroll
        for (int kk = 0; kk < BK; kk += 32) {
            short8v af[2], bfr[5];
            #pragma unroll
            for (int i = 0; i < 2; ++i)
                af[i] = *(const short8v*)(As + (wave * 32 + i * 16 + l16) * LDS_S + kk + quad * 8);
            #pragma unroll
            for (int j = 0; j < 5; ++j)
                bfr[j] = *(const short8v*)(Bs + (j * 16 + l16) * LDS_S + kk + quad * 8);
            #pragma unroll
            for (int i = 0; i < 2; ++i)
                #pragma unroll
                for (int j = 0; j < 5; ++j)
                    acc[i][j] = __builtin_amdgcn_mfma_f32_16x16x32_bf16(af[i], bfr[j], acc[i][j], 0, 0, 0);
        }
    }
    // epilogue: C store + per-column stats.  C/D layout: col=lane&15, row=quad*4+reg
    #pragma unroll
    for (int j = 0; j < 5; ++j) {
        int col = n0 + j * 16 + l16;
        float bv = bias[col];
        float s = 0.f, q = 0.f;
        #pragma unroll
        for (int i = 0; i < 2; ++i) {
            #pragma unroll
            for (int r = 0; r < 4; ++r) {
                int row = m0 + wave * 32 + i * 16 + quad * 4 + r;
                float v = acc[i][j][r] + bv;
                C[(size_t)row * ldc + col] = f2bf(v);
                s += v;
                q += v * v;
            }
        }
        s += __shfl_down(s, 32, 64); s += __shfl_down(s, 16, 64);
        q += __shfl_down(q, 32, 64); q += __shfl_down(q, 16, 64);
        if (lane < 16) { sred[wave][j][l16] = s; qred[wave][j][l16] = q; }
    }
    __syncthreads();
    if (tid < 80) {
        int j = tid >> 4, c = tid & 15;
        float S = sred[0][j][c] + sred[1][j][c] + sred[2][j][c] + sred[3][j][c];
        float Q = qred[0][j][c] + qred[1][j][c] + qred[2][j][c] + qred[3][j][c];
        int col = n0 + j * 16 + c;
        atomicAdd(&sums[col], S);
        atomicAdd(&sums[HID + col], Q);
    }
}

// ---------------- finalize: stats -> scale/shift ----------------
__global__ void finalize_kernel(const float* __restrict__ sums, const float* __restrict__ g,
                                const float* __restrict__ bt, float* __restrict__ scsh) {
    int j = threadIdx.x;
    if (j >= HID) return;
    const float invN = 1.f / (float)NROWS;
    float mu = sums[j] * invN;
    float var = sums[HID + j] * invN - mu * mu;
    float rstd = rsqrtf(var + BN_EPS);
    float sc = g[j] * rstd;
    scsh[j] = sc;
    scsh[HID + j] = bt[j] - mu * sc;
}

// ---------------- final: out[n] = f12[n] + sum_j relu(bn3(h3)) + bias ----------------
__global__ __launch_bounds__(256) void final_kernel(const unsigned short* __restrict__ H3,
                                                    const float* __restrict__ scsh,
                                                    const float* __restrict__ f12,
                                                    const float* __restrict__ bias,
                                                    float* __restrict__ out) {
    int wave = threadIdx.x >> 6, lane = threadIdx.x & 63;
    int n = blockIdx.x * 4 + wave;
    float acc = 0.f;
    for (int k = lane; k < HID; k += 64) {
        float v = bf2f(H3[(size_t)n * HID + k]) * scsh[k] + scsh[HID + k];
        acc += fmaxf(v, 0.f);
    }
    #pragma unroll
    for (int o = 32; o; o >>= 1) acc += __shfl_down(acc, o, 64);
    if (lane == 0) out[n] = acc + f12[n] + bias[0];
}

// ---------------- launch ----------------
extern "C" void kernel_launch(void* const* d_in, const int* in_sizes, int n_in,
                              void* d_out, int out_size, void* d_ws, size_t ws_size,
                              hipStream_t stream) {
    const int* Xi = (const int*)d_in[0];
    const float* Xv = (const float*)d_in[1];
    const float* emb1 = (const float*)d_in[2];
    const float* emb2 = (const float*)d_in[3];
    const float* W1 = (const float*)d_in[4];
    const float* b1 = (const float*)d_in[5];
    const float* g1 = (const float*)d_in[6];
    const float* bt1 = (const float*)d_in[7];
    const float* W2 = (const float*)d_in[8];
    const float* b2 = (const float*)d_in[9];
    const float* g2 = (const float*)d_in[10];
    const float* bt2 = (const float*)d_in[11];
    const float* W3 = (const float*)d_in[12];
    const float* b3 = (const float*)d_in[13];
    const float* g3 = (const float*)d_in[14];
    const float* bt3 = (const float*)d_in[15];
    const float* bias = (const float*)d_in[16];

    char* ws = (char*)d_ws;
    size_t o_f12 = 0;                                    // 64 KB
    size_t o_h0  = 65536;                                // 16384*624*2 = 20.4 MB  (also h2)
    size_t o_h1  = o_h0 + (size_t)NROWS * K1 * 2;        // 16384*400*2 = 13.1 MB  (also h3)
    size_t o_w1  = o_h1 + (size_t)NROWS * HID * 2;
    size_t o_w2  = o_w1 + (size_t)HID * K1T * 2;
    size_t o_w3  = o_w2 + (size_t)HID * K2T * 2;
    size_t o_sums = o_w3 + (size_t)HID * K2T * 2;        // 3*800*4
    size_t o_scsh = o_sums + 3 * 800 * 4;                // 3*800*4

    float* f12 = (float*)(ws + o_f12);
    unsigned short* h0 = (unsigned short*)(ws + o_h0);
    unsigned short* h1 = (unsigned short*)(ws + o_h1);
    unsigned short* h2 = (unsigned short*)(ws + o_h0);   // alias: h0 dead after gemm1
    unsigned short* h3 = (unsigned short*)(ws + o_h1);   // alias: h1 dead after gemm2
    unsigned short* w1b = (unsigned short*)(ws + o_w1);
    unsigned short* w2b = (unsigned short*)(ws + o_w2);
    unsigned short* w3b = (unsigned short*)(ws + o_w3);
    float* sums1 = (float*)(ws + o_sums);
    float* sums2 = sums1 + 800;
    float* sums3 = sums2 + 800;
    float* scsh1 = (float*)(ws + o_scsh);
    float* scsh2 = scsh1 + 800;
    float* scsh3 = scsh2 + 800;
    float* out = (float*)d_out;

    hipMemsetAsync(ws + o_sums, 0, 3 * 800 * 4, stream);

    convertw_kernel<<<dim3(HID, 3), K1T, 0, stream>>>(W1, W2, W3, w1b, w2b, w3b);
    embed_kernel<<<NROWS / 4, 256, 0, stream>>>(Xi, Xv, emb1, emb2, h0, f12);

    dim3 ggrid(NROWS / BM, HID / BNT);

    // layer 1: A = h0 (already normalized), stats fused
    gemm_kernel<false><<<ggrid, 256, 0, stream>>>(h0, K1, K1, w1b, K1T, b1, nullptr, h1, HID, K1T, sums1);
    finalize_kernel<<<1, 448, 0, stream>>>(sums1, g1, bt1, scsh1);

    // layer 2: A = h1 with fused BN1+ReLU, stats fused
    gemm_kernel<true><<<ggrid, 256, 0, stream>>>(h1, HID, HID, w2b, K2T, b2, scsh1, h2, HID, K2T, sums2);
    finalize_kernel<<<1, 448, 0, stream>>>(sums2, g2, bt2, scsh2);

    // layer 3: A = h2 with fused BN2+ReLU, stats fused
    gemm_kernel<true><<<ggrid, 256, 0, stream>>>(h2, HID, HID, w3b, K2T, b3, scsh2, h3, HID, K2T, sums3);
    finalize_kernel<<<1, 448, 0, stream>>>(sums3, g3, bt3, scsh3);

    // final: BN3+ReLU+rowsum + f12 + bias
    final_kernel<<<NROWS / 4, 256, 0, stream>>>(h3, scsh3, f12, bias, out);
}

// Round 3
// 433.589 us; speedup vs baseline: 1.2117x; 1.0545x over previous
//
#include <hip/hip_runtime.h>

// ---------------- constants ----------------
#define NROWS 16384
#define NF 39
#define NV 100000
#define NE 16
#define HID 400
#define K1 624     // real K of layer 1 (39*16)
#define K1T 640    // padded K span for layer 1
#define K2T 448    // padded K span for layers 2/3 (real 400)
#define BN_EPS 1e-5f

typedef short short8v __attribute__((ext_vector_type(8)));
typedef float float4v __attribute__((ext_vector_type(4)));

__device__ __forceinline__ float bf2f(unsigned short u) {
    unsigned int x = ((unsigned int)u) << 16;
    return __uint_as_float(x);
}
__device__ __forceinline__ unsigned short f2bf(float f) {
    unsigned int x = __float_as_uint(f);
    unsigned int r = (x + 0x7FFFu + ((x >> 16) & 1u)) >> 16;
    return (unsigned short)r;
}

// ---------------- embed: float4 gather + FM terms + h0 (bf16, unpadded 624) ----------------
__global__ __launch_bounds__(256) void embed_kernel(const int* __restrict__ Xi,
                                                    const float* __restrict__ Xv,
                                                    const float* __restrict__ emb1,
                                                    const float* __restrict__ emb2,
                                                    unsigned short* __restrict__ h0,
                                                    float* __restrict__ f12) {
    int wave = threadIdx.x >> 6, lane = threadIdx.x & 63;
    int n = blockIdx.x * 4 + wave;
    __shared__ int sidx[4][NF + 1];
    __shared__ float sxv[4][NF + 1];
    __shared__ __align__(16) float sx[4][NF * NE];
    __shared__ float srn[4][NE];
    if (lane < NF) {
        sidx[wave][lane] = Xi[n * NF + lane];
        sxv[wave][lane] = Xv[n * NF + lane];
    }
    __syncthreads();
    const float4* e2 = (const float4*)emb2;
    for (int i = lane; i < NF * 4; i += 64) {
        int f = i >> 2, q = i & 3;
        float4 v = e2[((size_t)f * NV + (size_t)sidx[wave][f]) * 4 + q];
        float m = sxv[wave][f];
        float4 o; o.x = v.x * m; o.y = v.y * m; o.z = v.z * m; o.w = v.w * m;
        *(float4*)&sx[wave][f * NE + q * 4] = o;
    }
    __syncthreads();
    float f2 = 0.f;
    if (lane < NE) {
        float ss = 0.f, sm = 0.f;
        #pragma unroll
        for (int f = 0; f < NF; ++f) {
            float v = sx[wave][f * NE + lane];
            ss += v * v;
            sm += v;
        }
        float rn = 1.f / fmaxf(sqrtf(ss), 1e-12f);
        srn[wave][lane] = rn;
        float s = sm * rn;
        f2 = 0.5f * (s * s - ss * rn * rn);
    }
    float f1 = 0.f;
    if (lane < NF) {
        f1 = emb1[(size_t)lane * NV + (size_t)sidx[wave][lane]] * sxv[wave][lane];
    }
    float tot = f1 + f2;
    #pragma unroll
    for (int o = 32; o; o >>= 1) tot += __shfl_down(tot, o, 64);
    if (lane == 0) f12[n] = tot;
    __syncthreads();
    for (int i = lane; i < NF * NE; i += 64)
        h0[(size_t)n * K1 + i] = f2bf(sx[wave][i] * srn[wave][i & 15]);
}

// ---------------- merged weight fp32 -> bf16 with K padding ----------------
__global__ __launch_bounds__(640) void convertw_kernel(const float* __restrict__ W1,
                                                       const float* __restrict__ W2,
                                                       const float* __restrict__ W3,
                                                       unsigned short* __restrict__ w1b,
                                                       unsigned short* __restrict__ w2b,
                                                       unsigned short* __restrict__ w3b) {
    int r = blockIdx.x, which = blockIdx.y, k = threadIdx.x;
    const float* W; unsigned short* O; int K, Kt;
    if (which == 0) { W = W1; O = w1b; K = K1;  Kt = K1T; }
    else if (which == 1) { W = W2; O = w2b; K = HID; Kt = K2T; }
    else { W = W3; O = w3b; K = HID; Kt = K2T; }
    if (k < Kt)
        O[(size_t)r * Kt + k] = (k < K) ? f2bf(W[(size_t)r * K + k]) : (unsigned short)0;
}

// ---------------- bf16 MFMA GEMM, register-prefetch staging, fused BN stats ----------------
// C[m,n] = sum_k A[m,k] * W[n,k] + bias[n]; per-column sum/sumsq atomically into `sums`.
// BM=128, BNT=80, BK=64. grid (128, 5), block 256 (4 waves).
#define BM 128
#define BNT 80
#define BK 64
#define LDS_S 72  // padded LDS k-stride (bf16 elems)

__global__ __launch_bounds__(256) void gemm_kernel(const unsigned short* __restrict__ A, int lda, int Kreal,
                                                   const unsigned short* __restrict__ W, int ldw,
                                                   const float* __restrict__ bias,
                                                   unsigned short* __restrict__ C, int ldc,
                                                   int Kt,
                                                   float* __restrict__ sums) {
    __shared__ __align__(16) unsigned short As[BM * LDS_S];
    __shared__ __align__(16) unsigned short Bs[BNT * LDS_S];
    __shared__ float sred[4][5][16], qred[4][5][16];
    int tid = threadIdx.x;
    int wave = tid >> 6, lane = tid & 63;
    int quad = lane >> 4, l16 = lane & 15;
    int m0 = blockIdx.x * BM;
    int n0 = blockIdx.y * BNT;

    short8v Ar[4], Br[3];
    const short8v zero8 = (short8v){0, 0, 0, 0, 0, 0, 0, 0};

    auto loadA = [&](int kt) {
        #pragma unroll
        for (int i = 0; i < 4; ++i) {
            int v = tid + i * 256;
            int r = v >> 3, k = kt + (v & 7) * 8;
            Ar[i] = (k < Kreal) ? *(const short8v*)(A + (size_t)(m0 + r) * lda + k) : zero8;
        }
    };
    auto loadB = [&](int kt) {
        #pragma unroll
        for (int i = 0; i < 3; ++i) {
            int v = tid + i * 256;
            if (v < BNT * 8) {
                int r = v >> 3, kv = (v & 7) * 8;
                Br[i] = *(const short8v*)(W + (size_t)(n0 + r) * ldw + kt + kv);
            }
        }
    };

    float4v acc[2][5];
    #pragma unroll
    for (int i = 0; i < 2; ++i)
        #pragma unroll
        for (int j = 0; j < 5; ++j)
            acc[i][j] = (float4v){0.f, 0.f, 0.f, 0.f};

    loadA(0);
    loadB(0);

    for (int kt = 0; kt < Kt; kt += BK) {
        // write current regs to LDS
        #pragma unroll
        for (int i = 0; i < 4; ++i) {
            int v = tid + i * 256;
            int r = v >> 3, kv = (v & 7) * 8;
            *(short8v*)(As + r * LDS_S + kv) = Ar[i];
        }
        #pragma unroll
        for (int i = 0; i < 3; ++i) {
            int v = tid + i * 256;
            if (v < BNT * 8) {
                int r = v >> 3, kv = (v & 7) * 8;
                *(short8v*)(Bs + r * LDS_S + kv) = Br[i];
            }
        }
        __syncthreads();
        // prefetch next tile into registers (latency overlaps compute below)
        if (kt + BK < Kt) {
            loadA(kt + BK);
            loadB(kt + BK);
        }
        // compute
        #pragma unroll
        for (int kk = 0; kk < BK; kk += 32) {
            short8v af[2], bfr[5];
            #pragma unroll
            for (int i = 0; i < 2; ++i)
                af[i] = *(const short8v*)(As + (wave * 32 + i * 16 + l16) * LDS_S + kk + quad * 8);
            #pragma unroll
            for (int j = 0; j < 5; ++j)
                bfr[j] = *(const short8v*)(Bs + (j * 16 + l16) * LDS_S + kk + quad * 8);
            #pragma unroll
            for (int i = 0; i < 2; ++i)
                #pragma unroll
                for (int j = 0; j < 5; ++j)
                    acc[i][j] = __builtin_amdgcn_mfma_f32_16x16x32_bf16(af[i], bfr[j], acc[i][j], 0, 0, 0);
        }
        __syncthreads();
    }
    // epilogue: store C + per-column stats. C/D layout: col=lane&15, row=quad*4+reg
    #pragma unroll
    for (int j = 0; j < 5; ++j) {
        int col = n0 + j * 16 + l16;
        float bv = bias[col];
        float s = 0.f, q = 0.f;
        #pragma unroll
        for (int i = 0; i < 2; ++i) {
            #pragma unroll
            for (int r = 0; r < 4; ++r) {
                int row = m0 + wave * 32 + i * 16 + quad * 4 + r;
                float v = acc[i][j][r] + bv;
                C[(size_t)row * ldc + col] = f2bf(v);
                s += v;
                q += v * v;
            }
        }
        s += __shfl_down(s, 32, 64); s += __shfl_down(s, 16, 64);
        q += __shfl_down(q, 32, 64); q += __shfl_down(q, 16, 64);
        if (lane < 16) { sred[wave][j][l16] = s; qred[wave][j][l16] = q; }
    }
    __syncthreads();
    if (tid < 80) {
        int j = tid >> 4, c = tid & 15;
        float S = sred[0][j][c] + sred[1][j][c] + sred[2][j][c] + sred[3][j][c];
        float Q = qred[0][j][c] + qred[1][j][c] + qred[2][j][c] + qred[3][j][c];
        int col = n0 + j * 16 + c;
        atomicAdd(&sums[col], S);
        atomicAdd(&sums[HID + col], Q);
    }
}

// ---------------- apply: finalize (in-block) + BN + ReLU -> padded bf16 (448) --------------
// grid 512 blocks x 256 thr, 32 rows/block, vectorized 8-wide.
__global__ __launch_bounds__(256) void apply_kernel(const unsigned short* __restrict__ H,
                                                    const float* __restrict__ sums,
                                                    const float* __restrict__ g,
                                                    const float* __restrict__ bt,
                                                    unsigned short* __restrict__ Aout) {
    __shared__ float ssc[HID], ssh[HID];
    int tid = threadIdx.x;
    const float invN = 1.f / (float)NROWS;
    for (int j = tid; j < HID; j += 256) {
        float mu = sums[j] * invN;
        float var = sums[HID + j] * invN - mu * mu;
        float rstd = rsqrtf(var + BN_EPS);
        float sc = g[j] * rstd;
        ssc[j] = sc;
        ssh[j] = bt[j] - mu * sc;
    }
    __syncthreads();
    int row0 = blockIdx.x * 32;
    // 32 rows x 50 vec8 chunks of payload
    for (int idx = tid; idx < 32 * 50; idx += 256) {
        int r = idx / 50, c = (idx % 50) * 8;
        short8v v = *(const short8v*)(H + (size_t)(row0 + r) * HID + c);
        short8v o;
        #pragma unroll
        for (int e = 0; e < 8; ++e) {
            float x = bf2f((unsigned short)v[e]);
            o[e] = (short)f2bf(fmaxf(x * ssc[c + e] + ssh[c + e], 0.f));
        }
        *(short8v*)(Aout + (size_t)(row0 + r) * K2T + c) = o;
    }
    // zero the 48-col pad: 32 rows x 6 vec8
    const short8v zero8 = (short8v){0, 0, 0, 0, 0, 0, 0, 0};
    for (int idx = tid; idx < 32 * 6; idx += 256) {
        int r = idx / 6, c = HID + (idx % 6) * 8;
        *(short8v*)(Aout + (size_t)(row0 + r) * K2T + c) = zero8;
    }
}

// ---------------- final: finalize3 (in-block) + BN3+ReLU+rowsum + f12 + bias ----------------
__global__ __launch_bounds__(256) void final_kernel(const unsigned short* __restrict__ H3,
                                                    const float* __restrict__ sums,
                                                    const float* __restrict__ g,
                                                    const float* __restrict__ bt,
                                                    const float* __restrict__ f12,
                                                    const float* __restrict__ bias,
                                                    float* __restrict__ out) {
    __shared__ float ssc[HID], ssh[HID];
    int tid = threadIdx.x;
    const float invN = 1.f / (float)NROWS;
    for (int j = tid; j < HID; j += 256) {
        float mu = sums[j] * invN;
        float var = sums[HID + j] * invN - mu * mu;
        float rstd = rsqrtf(var + BN_EPS);
        float sc = g[j] * rstd;
        ssc[j] = sc;
        ssh[j] = bt[j] - mu * sc;
    }
    __syncthreads();
    int wave = tid >> 6, lane = tid & 63;
    int n = blockIdx.x * 4 + wave;
    float acc = 0.f;
    for (int k = lane; k < HID; k += 64) {
        float v = bf2f(H3[(size_t)n * HID + k]) * ssc[k] + ssh[k];
        acc += fmaxf(v, 0.f);
    }
    #pragma unroll
    for (int o = 32; o; o >>= 1) acc += __shfl_down(acc, o, 64);
    if (lane == 0) out[n] = acc + f12[n] + bias[0];
}

// ---------------- launch ----------------
extern "C" void kernel_launch(void* const* d_in, const int* in_sizes, int n_in,
                              void* d_out, int out_size, void* d_ws, size_t ws_size,
                              hipStream_t stream) {
    const int* Xi = (const int*)d_in[0];
    const float* Xv = (const float*)d_in[1];
    const float* emb1 = (const float*)d_in[2];
    const float* emb2 = (const float*)d_in[3];
    const float* W1 = (const float*)d_in[4];
    const float* b1 = (const float*)d_in[5];
    const float* g1 = (const float*)d_in[6];
    const float* bt1 = (const float*)d_in[7];
    const float* W2 = (const float*)d_in[8];
    const float* b2 = (const float*)d_in[9];
    const float* g2 = (const float*)d_in[10];
    const float* bt2 = (const float*)d_in[11];
    const float* W3 = (const float*)d_in[12];
    const float* b3 = (const float*)d_in[13];
    const float* g3 = (const float*)d_in[14];
    const float* bt3 = (const float*)d_in[15];
    const float* bias = (const float*)d_in[16];

    char* ws = (char*)d_ws;
    size_t o_f12 = 0;                                    // 64 KB
    size_t o_h0  = 65536;                                // 16384*624*2 (h0; later h2's a-input scratch)
    size_t o_h1  = o_h0 + (size_t)NROWS * K1 * 2;        // 16384*400*2 (h1, later h3)
    size_t o_a1  = o_h1 + (size_t)NROWS * HID * 2;       // 16384*448*2 (a1, later a2)
    size_t o_w1  = o_a1 + (size_t)NROWS * K2T * 2;
    size_t o_w2  = o_w1 + (size_t)HID * K1T * 2;
    size_t o_w3  = o_w2 + (size_t)HID * K2T * 2;
    size_t o_sums = o_w3 + (size_t)HID * K2T * 2;        // 3*800*4

    float* f12 = (float*)(ws + o_f12);
    unsigned short* h0 = (unsigned short*)(ws + o_h0);
    unsigned short* h1 = (unsigned short*)(ws + o_h1);
    unsigned short* a1 = (unsigned short*)(ws + o_a1);
    unsigned short* h2 = (unsigned short*)(ws + o_h0);   // alias: h0 dead after gemm1
    unsigned short* a2 = (unsigned short*)(ws + o_a1);   // alias: a1 dead after gemm2
    unsigned short* h3 = (unsigned short*)(ws + o_h1);   // alias: h1 dead after apply1
    unsigned short* w1b = (unsigned short*)(ws + o_w1);
    unsigned short* w2b = (unsigned short*)(ws + o_w2);
    unsigned short* w3b = (unsigned short*)(ws + o_w3);
    float* sums1 = (float*)(ws + o_sums);
    float* sums2 = sums1 + 800;
    float* sums3 = sums2 + 800;
    float* out = (float*)d_out;

    hipMemsetAsync(ws + o_sums, 0, 3 * 800 * 4, stream);

    convertw_kernel<<<dim3(HID, 3), K1T, 0, stream>>>(W1, W2, W3, w1b, w2b, w3b);
    embed_kernel<<<NROWS / 4, 256, 0, stream>>>(Xi, Xv, emb1, emb2, h0, f12);

    dim3 ggrid(NROWS / BM, HID / BNT);

    // layer 1
    gemm_kernel<<<ggrid, 256, 0, stream>>>(h0, K1, K1, w1b, K1T, b1, h1, HID, K1T, sums1);
    apply_kernel<<<NROWS / 32, 256, 0, stream>>>(h1, sums1, g1, bt1, a1);

    // layer 2
    gemm_kernel<<<ggrid, 256, 0, stream>>>(a1, K2T, K2T, w2b, K2T, b2, h2, HID, K2T, sums2);
    apply_kernel<<<NROWS / 32, 256, 0, stream>>>(h2, sums2, g2, bt2, a2);

    // layer 3
    gemm_kernel<<<ggrid, 256, 0, stream>>>(a2, K2T, K2T, w3b, K2T, b3, h3, HID, K2T, sums3);

    // final
    final_kernel<<<NROWS / 4, 256, 0, stream>>>(h3, sums3, g3, bt3, f12, bias, out);
}

// Round 6
// 417.885 us; speedup vs baseline: 1.2572x; 1.0376x over previous
//
#include <hip/hip_runtime.h>

// ---------------- constants ----------------
#define NROWS 16384
#define NF 39
#define NV 100000
#define NE 16
#define HID 400
#define K1 624     // real K of layer 1 (39*16)
#define K1T 640    // padded K span for layer 1
#define K2T 448    // padded K span for layers 2/3 (real 400)
#define BN_EPS 1e-5f

typedef short short8v __attribute__((ext_vector_type(8)));
typedef float float4v __attribute__((ext_vector_type(4)));

__device__ __forceinline__ float bf2f(unsigned short u) {
    unsigned int x = ((unsigned int)u) << 16;
    return __uint_as_float(x);
}
__device__ __forceinline__ unsigned short f2bf(float f) {
    unsigned int x = __float_as_uint(f);
    unsigned int r = (x + 0x7FFFu + ((x >> 16) & 1u)) >> 16;
    return (unsigned short)r;
}

// ---------------- prep: embed (blocks 0..4095) + weight-convert + zero sums -------------
#define EMB_BLOCKS 4096
#define W1E (448 * 640)           // 286720
#define W2E (448 * 448)           // 200704
#define TCVT (W1E + 2 * W2E)      // 688128 elems
#define CVT_BLOCKS (TCVT / 8 / 256)   // 336

__global__ __launch_bounds__(256) void prep_kernel(const int* __restrict__ Xi,
                                                   const float* __restrict__ Xv,
                                                   const float* __restrict__ emb1,
                                                   const float* __restrict__ emb2,
                                                   const float* __restrict__ W1,
                                                   const float* __restrict__ W2,
                                                   const float* __restrict__ W3,
                                                   unsigned short* __restrict__ h0,
                                                   float* __restrict__ f12,
                                                   unsigned short* __restrict__ w1b,
                                                   unsigned short* __restrict__ w2b,
                                                   unsigned short* __restrict__ w3b,
                                                   float* __restrict__ sums) {
    int b = blockIdx.x;
    int tid = threadIdx.x;
    if (b < EMB_BLOCKS) {
        int wave = tid >> 6, lane = tid & 63;
        int n = b * 4 + wave;
        __shared__ int sidx[4][NF + 1];
        __shared__ float sxv[4][NF + 1];
        __shared__ __align__(16) float sx[4][NF * NE];
        __shared__ float srn[4][NE];
        if (lane < NF) {
            sidx[wave][lane] = Xi[n * NF + lane];
            sxv[wave][lane] = Xv[n * NF + lane];
        }
        __syncthreads();
        const float4* e2 = (const float4*)emb2;
        for (int i = lane; i < NF * 4; i += 64) {
            int f = i >> 2, q = i & 3;
            float4 v = e2[((size_t)f * NV + (size_t)sidx[wave][f]) * 4 + q];
            float m = sxv[wave][f];
            float4 o; o.x = v.x * m; o.y = v.y * m; o.z = v.z * m; o.w = v.w * m;
            *(float4*)&sx[wave][f * NE + q * 4] = o;
        }
        __syncthreads();
        float f2 = 0.f;
        if (lane < NE) {
            float ss = 0.f, sm = 0.f;
            #pragma unroll
            for (int f = 0; f < NF; ++f) {
                float v = sx[wave][f * NE + lane];
                ss += v * v;
                sm += v;
            }
            float rn = 1.f / fmaxf(sqrtf(ss), 1e-12f);
            srn[wave][lane] = rn;
            float s = sm * rn;
            f2 = 0.5f * (s * s - ss * rn * rn);
        }
        float f1 = 0.f;
        if (lane < NF) {
            f1 = emb1[(size_t)lane * NV + (size_t)sidx[wave][lane]] * sxv[wave][lane];
        }
        float tot = f1 + f2;
        #pragma unroll
        for (int o = 32; o; o >>= 1) tot += __shfl_down(tot, o, 64);
        if (lane == 0) f12[n] = tot;
        __syncthreads();
        // h0 store: 78 vec8 chunks per row, 64 lanes -> STRIDED (2 iterations).
        // (R4/R5 bug: `if (lane < 78)` with 64 lanes left cols 512..623 unwritten.)
        for (int i = lane; i < 78; i += 64) {
            int k0 = i * 8;
            short8v o;
            #pragma unroll
            for (int e = 0; e < 8; ++e) {
                int k = k0 + e;
                o[e] = (short)f2bf(sx[wave][k] * srn[wave][k & 15]);
            }
            *(short8v*)(h0 + (size_t)n * K1 + k0) = o;
        }
        return;
    }
    b -= EMB_BLOCKS;
    if (b < CVT_BLOCKS) {
        int gidx = b * 256 + tid;
        int e = gidx * 8;
        if (e < TCVT) {
            const float* W; unsigned short* O; int Kreal, Kt, base;
            if (e < W1E) { W = W1; O = w1b; Kreal = K1; Kt = K1T; base = 0; }
            else if (e < W1E + W2E) { W = W2; O = w2b; Kreal = HID; Kt = K2T; base = W1E; }
            else { W = W3; O = w3b; Kreal = HID; Kt = K2T; base = W1E + W2E; }
            int le = e - base;
            int r = le / Kt, k = le % Kt;
            short8v o;
            #pragma unroll
            for (int ee = 0; ee < 8; ++ee) {
                int kk = k + ee;
                o[ee] = (r < HID && kk < Kreal) ? (short)f2bf(W[(size_t)r * Kreal + kk]) : (short)0;
            }
            *(short8v*)(O + (size_t)r * Kt + k) = o;
        }
        return;
    }
    for (int i = tid; i < 2400; i += 256) sums[i] = 0.f;
}

// ---------------- bf16 MFMA GEMM: 512 thr, BM=128, BNT=224, fused BN-apply + BN-stats -----
#define BM 128
#define BNT 224
#define BK 64
#define LDS_S 72  // padded LDS k-stride (bf16 elems)

template <bool FUSE_BN>
__global__ __launch_bounds__(512, 2) void gemm_kernel(const unsigned short* __restrict__ A,
                                                      int lda, int Kreal, int Kt,
                                                      const unsigned short* __restrict__ W,  // 448 x Kt
                                                      const float* __restrict__ bias,
                                                      const float* __restrict__ psums,
                                                      const float* __restrict__ g,
                                                      const float* __restrict__ bt,
                                                      unsigned short* __restrict__ C,        // ldc = 400
                                                      float* __restrict__ sums) {
    __shared__ __align__(16) unsigned short As[BM * LDS_S];
    __shared__ __align__(16) unsigned short Bs[BNT * LDS_S];
    __shared__ float ssc[K2T], ssh[K2T];
    __shared__ float scol[BNT], qcol[BNT];
    int tid = threadIdx.x;
    int wave = tid >> 6, lane = tid & 63;
    int quad = lane >> 4, l16 = lane & 15;
    int mi = wave & 3, nj = wave >> 2;
    int m0 = blockIdx.x * BM;
    int n0 = blockIdx.y * BNT;

    if (FUSE_BN && tid < K2T) {
        float sc = 0.f, sh = 0.f;
        if (tid < HID) {
            const float invN = 1.f / (float)NROWS;
            float mu = psums[tid] * invN;
            float var = psums[HID + tid] * invN - mu * mu;
            float rstd = rsqrtf(var + BN_EPS);
            sc = g[tid] * rstd;
            sh = bt[tid] - mu * sc;
        }
        ssc[tid] = sc; ssh[tid] = sh;
    }
    if (tid < BNT) { scol[tid] = 0.f; qcol[tid] = 0.f; }

    short8v Ar[2], Br[4];
    const short8v zero8 = (short8v){0, 0, 0, 0, 0, 0, 0, 0};

    auto loadA = [&](int kt) {
        #pragma unroll
        for (int i = 0; i < 2; ++i) {
            int v = tid + i * 512;
            int r = v >> 3, k = kt + (v & 7) * 8;
            Ar[i] = (k < Kreal) ? *(const short8v*)(A + (size_t)(m0 + r) * lda + k) : zero8;
        }
    };
    auto loadB = [&](int kt) {
        #pragma unroll
        for (int i = 0; i < 4; ++i) {
            int v = tid + i * 512;
            if (v < BNT * 8) {
                int r = v >> 3, kv = (v & 7) * 8;
                Br[i] = *(const short8v*)(W + (size_t)(n0 + r) * Kt + kt + kv);
            }
        }
    };

    float4v acc[2][7];
    #pragma unroll
    for (int i = 0; i < 2; ++i)
        #pragma unroll
        for (int f = 0; f < 7; ++f)
            acc[i][f] = (float4v){0.f, 0.f, 0.f, 0.f};

    loadA(0);
    loadB(0);
    __syncthreads();   // ssc/ssh + scol ready

    for (int kt = 0; kt < Kt; kt += BK) {
        #pragma unroll
        for (int i = 0; i < 2; ++i) {
            int v = tid + i * 512;
            int r = v >> 3, kv = (v & 7) * 8;
            short8v val = Ar[i];
            if (FUSE_BN) {
                #pragma unroll
                for (int e = 0; e < 8; ++e) {
                    int k = kt + kv + e;
                    float x = bf2f((unsigned short)val[e]);
                    val[e] = (short)f2bf(fmaxf(x * ssc[k] + ssh[k], 0.f));
                }
            }
            *(short8v*)(As + r * LDS_S + kv) = val;
        }
        #pragma unroll
        for (int i = 0; i < 4; ++i) {
            int v = tid + i * 512;
            if (v < BNT * 8) {
                int r = v >> 3, kv = (v & 7) * 8;
                *(short8v*)(Bs + r * LDS_S + kv) = Br[i];
            }
        }
        __syncthreads();
        if (kt + BK < Kt) { loadA(kt + BK); loadB(kt + BK); }
        #pragma unroll
        for (int kk = 0; kk < BK; kk += 32) {
            short8v af[2], bfr[7];
            #pragma unroll
            for (int i = 0; i < 2; ++i)
                af[i] = *(const short8v*)(As + (mi * 32 + i * 16 + l16) * LDS_S + kk + quad * 8);
            #pragma unroll
            for (int f = 0; f < 7; ++f)
                bfr[f] = *(const short8v*)(Bs + (nj * 112 + f * 16 + l16) * LDS_S + kk + quad * 8);
            #pragma unroll
            for (int i = 0; i < 2; ++i)
                #pragma unroll
                for (int f = 0; f < 7; ++f)
                    acc[i][f] = __builtin_amdgcn_mfma_f32_16x16x32_bf16(af[i], bfr[f], acc[i][f], 0, 0, 0);
        }
        __syncthreads();
    }

    // epilogue: store C + per-column stats. C/D layout: col=lane&15, row=quad*4+reg
    #pragma unroll
    for (int f = 0; f < 7; ++f) {
        int lc = nj * 112 + f * 16 + l16;
        int col = n0 + lc;
        float bv = (col < HID) ? bias[col] : 0.f;
        float s = 0.f, q = 0.f;
        #pragma unroll
        for (int i = 0; i < 2; ++i) {
            #pragma unroll
            for (int r = 0; r < 4; ++r) {
                int row = m0 + mi * 32 + i * 16 + quad * 4 + r;
                float v = acc[i][f][r] + bv;
                if (col < HID) C[(size_t)row * HID + col] = f2bf(v);
                s += v;
                q += v * v;
            }
        }
        s += __shfl_down(s, 32, 64); s += __shfl_down(s, 16, 64);
        q += __shfl_down(q, 32, 64); q += __shfl_down(q, 16, 64);
        if (lane < 16) {
            atomicAdd(&scol[lc], s);
            atomicAdd(&qcol[lc], q);
        }
    }
    __syncthreads();
    if (tid < BNT) {
        int col = n0 + tid;
        if (col < HID) {
            atomicAdd(&sums[col], scol[tid]);
            atomicAdd(&sums[HID + col], qcol[tid]);
        }
    }
}

// ---------------- final: finalize3 (in-block, strided fill) + BN3+ReLU+rowsum --------------
__global__ __launch_bounds__(256) void final_kernel(const unsigned short* __restrict__ H3,
                                                    const float* __restrict__ sums,
                                                    const float* __restrict__ g,
                                                    const float* __restrict__ bt,
                                                    const float* __restrict__ f12,
                                                    const float* __restrict__ bias,
                                                    float* __restrict__ out) {
    __shared__ float ssc[HID], ssh[HID];
    int tid = threadIdx.x;
    const float invN = 1.f / (float)NROWS;
    for (int j = tid; j < HID; j += 256) {   // strided: 256 threads cover 400 columns
        float mu = sums[j] * invN;
        float var = sums[HID + j] * invN - mu * mu;
        float rstd = rsqrtf(var + BN_EPS);
        float sc = g[j] * rstd;
        ssc[j] = sc;
        ssh[j] = bt[j] - mu * sc;
    }
    __syncthreads();
    int wave = tid >> 6, lane = tid & 63;
    int n = blockIdx.x * 4 + wave;
    float acc = 0.f;
    if (lane < 50) {
        short8v v = *(const short8v*)(H3 + (size_t)n * HID + lane * 8);
        #pragma unroll
        for (int e = 0; e < 8; ++e) {
            int k = lane * 8 + e;
            float x = bf2f((unsigned short)v[e]) * ssc[k] + ssh[k];
            acc += fmaxf(x, 0.f);
        }
    }
    #pragma unroll
    for (int o = 32; o; o >>= 1) acc += __shfl_down(acc, o, 64);
    if (lane == 0) out[n] = acc + f12[n] + bias[0];
}

// ---------------- launch ----------------
extern "C" void kernel_launch(void* const* d_in, const int* in_sizes, int n_in,
                              void* d_out, int out_size, void* d_ws, size_t ws_size,
                              hipStream_t stream) {
    const int* Xi = (const int*)d_in[0];
    const float* Xv = (const float*)d_in[1];
    const float* emb1 = (const float*)d_in[2];
    const float* emb2 = (const float*)d_in[3];
    const float* W1 = (const float*)d_in[4];
    const float* b1 = (const float*)d_in[5];
    const float* g1 = (const float*)d_in[6];
    const float* bt1 = (const float*)d_in[7];
    const float* W2 = (const float*)d_in[8];
    const float* b2 = (const float*)d_in[9];
    const float* g2 = (const float*)d_in[10];
    const float* bt2 = (const float*)d_in[11];
    const float* W3 = (const float*)d_in[12];
    const float* b3 = (const float*)d_in[13];
    const float* g3 = (const float*)d_in[14];
    const float* bt3 = (const float*)d_in[15];
    const float* bias = (const float*)d_in[16];

    char* ws = (char*)d_ws;
    size_t o_f12 = 0;
    size_t o_h0  = 65536;
    size_t o_h1  = o_h0 + (size_t)NROWS * K1 * 2;
    size_t o_w1  = o_h1 + (size_t)NROWS * HID * 2;
    size_t o_w2  = o_w1 + (size_t)448 * K1T * 2;
    size_t o_w3  = o_w2 + (size_t)448 * K2T * 2;
    size_t o_sums = o_w3 + (size_t)448 * K2T * 2;

    float* f12 = (float*)(ws + o_f12);
    unsigned short* h0 = (unsigned short*)(ws + o_h0);
    unsigned short* h1 = (unsigned short*)(ws + o_h1);
    unsigned short* h2 = (unsigned short*)(ws + o_h0);   // alias: h0 dead after gemm1
    unsigned short* h3 = (unsigned short*)(ws + o_h1);   // alias: h1 dead after gemm2
    unsigned short* w1b = (unsigned short*)(ws + o_w1);
    unsigned short* w2b = (unsigned short*)(ws + o_w2);
    unsigned short* w3b = (unsigned short*)(ws + o_w3);
    float* sums1 = (float*)(ws + o_sums);
    float* sums2 = sums1 + 800;
    float* sums3 = sums2 + 800;
    float* out = (float*)d_out;

    prep_kernel<<<EMB_BLOCKS + CVT_BLOCKS + 1, 256, 0, stream>>>(
        Xi, Xv, emb1, emb2, W1, W2, W3, h0, f12, w1b, w2b, w3b, sums1);

    dim3 ggrid(NROWS / BM, 2);

    gemm_kernel<false><<<ggrid, 512, 0, stream>>>(h0, K1, K1, K1T, w1b, b1,
                                                  nullptr, nullptr, nullptr, h1, sums1);
    gemm_kernel<true><<<ggrid, 512, 0, stream>>>(h1, HID, HID, K2T, w2b, b2,
                                                 sums1, g1, bt1, h2, sums2);
    gemm_kernel<true><<<ggrid, 512, 0, stream>>>(h2, HID, HID, K2T, w3b, b3,
                                                 sums2, g2, bt2, h3, sums3);
    final_kernel<<<NROWS / 4, 256, 0, stream>>>(h3, sums3, g3, bt3, f12, bias, out);
}